// Round 7
// baseline (427.382 us; speedup 1.0000x reference)
//
#include <hip/hip_runtime.h>
#include <math.h>

// Equivariant graph attention (Transformer_79302276153378), MI355X.
// Round 7: single-pass fusion. sqrt(alpha)=sqrt(expw)/sqrt(z) -> z pulled out
// to node_out, so value accumulation fuses into edge_gemm: per-block segmented
// reduction into a 32-slot LDS U buffer (aliased onto W2hl after MFMA), flush
// per distinct dst (store if interior, atomic if boundary). Kills value_kernel,
// the 2nd random node_f gather, and the 82MB Avb round-trip.

constexpr int NN = 20000;
constexpr int NE = 320000;
constexpr float INV3      = 0.57735026918962576f;  // 1/sqrt(3)
constexpr float INV_SQRT8 = 0.35355339059327373f;  // 1/sqrt(R_DIM)

typedef __attribute__((ext_vector_type(8))) short bf16x8;
typedef __attribute__((ext_vector_type(4))) float f32x4;

__device__ __forceinline__ float gelu_tanh(float p) {
    float y = 0.7978845608028654f * (p + 0.044715f * p * p * p);
    return p / (1.0f + __expf(-2.0f * y));
}
__device__ __forceinline__ ushort bf16_rn(float f) {
    unsigned u = __float_as_uint(f);
    unsigned r = (u + 0x7FFFu + ((u >> 16) & 1u)) >> 16;
    return (ushort)r;
}
__device__ __forceinline__ float bf16_f(ushort h) {
    return __uint_as_float(((unsigned)h) << 16);
}

// ---------------- K0: per-node dst transform ----------------
__global__ __launch_bounds__(256) void node_transform_kernel(
    const float* __restrict__ node_f,
    const float* __restrict__ w_ss,
    const float* __restrict__ w_vv,
    float* __restrict__ t)            // (NN,32,8)
{
    __shared__ float lws[2048];
    __shared__ float lwv[2048];
    const int tid = threadIdx.x;
    for (int i = tid; i < 2048; i += 256) { lws[i] = w_ss[i]; lwv[i] = w_vv[i]; }
    __syncthreads();

    const int idx = blockIdx.x * 256 + tid;
    if (idx >= NN * 32) return;
    const int n = idx >> 5, v = idx & 31;
    const float* nf = node_f + (size_t)n * 128;

    float t0 = 0.f, t1 = 0.f;
    float tv00 = 0.f, tv01 = 0.f, tv02 = 0.f;
    float tv10 = 0.f, tv11 = 0.f, tv12 = 0.f;
    #pragma unroll
    for (int u = 0; u < 32; ++u) {
        const float s  = nf[u];
        const float vx = nf[32 + 3*u + 0];
        const float vy = nf[32 + 3*u + 1];
        const float vz = nf[32 + 3*u + 2];
        const float a = lws[u*32 + v];
        const float b = lws[1024 + u*32 + v];
        const float c = lwv[u*32 + v];
        const float d = lwv[1024 + u*32 + v];
        t0 = fmaf(s, a, t0);  t1 = fmaf(s, b, t1);
        tv00 = fmaf(vx, c, tv00); tv01 = fmaf(vy, c, tv01); tv02 = fmaf(vz, c, tv02);
        tv10 = fmaf(vx, d, tv10); tv11 = fmaf(vy, d, tv11); tv12 = fmaf(vz, d, tv12);
    }
    float4* o = (float4*)(t + (size_t)idx * 8);
    o[0] = make_float4(t0, t1, tv00 * INV3, tv01 * INV3);
    o[1] = make_float4(tv02 * INV3, tv10 * INV3, tv11 * INV3, tv12 * INV3);
}

// ---------------- w2 -> pre-swizzled bf16 hi/lo image (one-time) -------------
__global__ __launch_bounds__(256) void w2img_kernel(
    const float* __restrict__ k_w2, const float* __restrict__ v_w2,
    ushort* __restrict__ img)
{
    const int i = blockIdx.x * 256 + threadIdx.x;   // 0..16383
    if (i >= 16384) return;
    const int ph = i >> 13, r = i & 8191;
    const int k = r >> 7, n = r & 127;
    const float f = (ph ? v_w2 : k_w2)[r];
    const ushort hi = bf16_rn(f);
    const ushort lo = bf16_rn(f - bf16_f(hi));
    const int sw = (n << 6) | (k ^ ((n & 7) << 3));
    img[(size_t)ph * 16384 + sw] = hi;
    img[(size_t)ph * 16384 + 8192 + sw] = lo;
}

// ---------------- CSR build ----------------
__global__ __launch_bounds__(256) void hist_kernel(
    const int* __restrict__ edst, int* __restrict__ cnt)
{
    const int e = blockIdx.x * 256 + threadIdx.x;
    if (e < NE) atomicAdd(&cnt[edst[e]], 1);
}

__global__ __launch_bounds__(256) void scanA_kernel(
    const int* __restrict__ cnt, int* __restrict__ rowptr, int* __restrict__ bsum)
{
    __shared__ int buf[256];
    const int i = blockIdx.x * 256 + threadIdx.x;
    const int v = (i < NN) ? cnt[i] : 0;
    buf[threadIdx.x] = v;
    __syncthreads();
    #pragma unroll
    for (int off = 1; off < 256; off <<= 1) {
        const int tc = (threadIdx.x >= off) ? buf[threadIdx.x - off] : 0;
        __syncthreads();
        buf[threadIdx.x] += tc;
        __syncthreads();
    }
    if (i < NN) rowptr[i] = buf[threadIdx.x] - v;       // local exclusive
    if (threadIdx.x == 255) bsum[blockIdx.x] = buf[255];
}

__global__ __launch_bounds__(128) void scanB_kernel(
    const int* __restrict__ bsum, int* __restrict__ boff, int* __restrict__ rowptr)
{
    __shared__ int b[128];
    const int tid = threadIdx.x;
    const int v = (tid < 79) ? bsum[tid] : 0;
    b[tid] = v;
    __syncthreads();
    #pragma unroll
    for (int off = 1; off < 128; off <<= 1) {
        const int tc = (tid >= off) ? b[tid - off] : 0;
        __syncthreads();
        b[tid] += tc;
        __syncthreads();
    }
    boff[tid] = b[tid] - v;                             // exclusive
    if (tid == 0) rowptr[NN] = NE;
}

__global__ __launch_bounds__(256) void scanC_kernel(
    int* __restrict__ rowptr, const int* __restrict__ boff, int* __restrict__ woff)
{
    const int i = blockIdx.x * 256 + threadIdx.x;
    if (i < NN) {
        const int r = rowptr[i] + boff[blockIdx.x];
        rowptr[i] = r;
        woff[i] = r;
    }
}

__global__ __launch_bounds__(256) void scatter_kernel(
    const int* __restrict__ edst, int* __restrict__ woff, int* __restrict__ perm)
{
    const int e = blockIdx.x * 256 + threadIdx.x;
    if (e < NE) {
        const int pos = atomicAdd(&woff[edst[e]], 1);
        perm[pos] = e;
    }
}

// ---------------- fused edge kernel: GEMMs + logit + value accumulation ------
// 64 CSR slots/block, 256 threads (4 waves x 16-edge M-tile).
__global__ __launch_bounds__(256, 3) void edge_gemm_kernel(
    const int*   __restrict__ perm,
    const int*   __restrict__ esrc,
    const int*   __restrict__ edst,
    const float* __restrict__ xattr,
    const float* __restrict__ eattr,
    const float* __restrict__ cutoff,
    const float* __restrict__ node_f,
    const float* __restrict__ k_w1,
    const float* __restrict__ v_w1,
    const ushort* __restrict__ w2img,  // pre-swizzled hi/lo, 2 phases
    const float* __restrict__ t,       // (NN,256)
    const int*   __restrict__ rowptr,
    float* __restrict__ z,             // (NN,) atomic
    float* __restrict__ accg)          // (NN,256) [v][8] layout, atomic/store
{
    __shared__ ushort W2hl[16384];            // 32KB; aliased as U[32][256] f32
    __shared__ ushort Hh[4096], Hl[4096];     // [e:64][k:64] swizzled
    __shared__ __align__(16) float xs[64][8];
    __shared__ float  seat[64][4];
    __shared__ float  cut[64], sexp[64];
    __shared__ int    sdst[64], ssrc[64], eid[64], slot[64], sdstu[64];
    __shared__ int    nslots_s;

    const int tid  = threadIdx.x;
    const int e0   = blockIdx.x * 64;          // CSR base
    const int lane = tid & 63, wv = tid >> 6;
    const int c    = lane & 15, g = lane >> 4;
    const int j    = lane;                     // hidden index for H compute

    if (tid < 64) {
        const int e = perm[e0 + tid];
        eid[tid] = e; sdst[tid] = edst[e]; ssrc[tid] = esrc[e];
        cut[tid] = cutoff[e];
    }
    __syncthreads();
    if (tid < 64) {                            // wave-0 segmented slot scan
        const int flag = (tid == 0) ? 1 : ((sdst[tid] != sdst[tid-1]) ? 1 : 0);
        int s = flag;
        #pragma unroll
        for (int m = 1; m < 64; m <<= 1) {
            const int o = __shfl_up(s, m, 64);
            if (tid >= m) s += o;
        }
        slot[tid] = s - 1;
        if (flag) sdstu[s - 1] = sdst[tid];
        if (tid == 63) nslots_s = s;
    }
    {
        int i = tid;
        xs[i >> 3][i & 7] = xattr[(size_t)eid[i >> 3]*8 + (i & 7)];
        i = tid + 256;
        xs[i >> 3][i & 7] = xattr[(size_t)eid[i >> 3]*8 + (i & 7)];
        seat[tid >> 2][tid & 3] = eattr[(size_t)eid[tid >> 2]*4 + (tid & 3)];
    }

    for (int ph = 0; ph < 2; ++ph) {
        const float* w1 = ph ? v_w1 : k_w1;
        __syncthreads();   // staging visible (ph0) / ph0 fully done (ph1)

        // linear 32KB copy of pre-swizzled w2 image -> LDS (conflict-free)
        {
            uint4* d = (uint4*)W2hl;
            const uint4* s = (const uint4*)(w2img + (size_t)ph * 16384);
            #pragma unroll
            for (int i = tid; i < 2048; i += 256) d[i] = s[i];
        }
        // H = gelu(x @ w1 / sqrt(8)), bf16 split, swizzled store
        {
            float w1c[8];
            #pragma unroll
            for (int r = 0; r < 8; ++r) w1c[r] = w1[r*64 + j];
            #pragma unroll
            for (int tt = 0; tt < 16; ++tt) {
                const int e = (tid >> 6) + 4*tt;
                const float4* xp = (const float4*)xs[e];
                const float4 x0 = xp[0], x1 = xp[1];
                float p = x0.x*w1c[0];
                p = fmaf(x0.y, w1c[1], p); p = fmaf(x0.z, w1c[2], p);
                p = fmaf(x0.w, w1c[3], p); p = fmaf(x1.x, w1c[4], p);
                p = fmaf(x1.y, w1c[5], p); p = fmaf(x1.z, w1c[6], p);
                p = fmaf(x1.w, w1c[7], p);
                const float h = gelu_tanh(p * INV_SQRT8);
                const ushort hi = bf16_rn(h);
                const ushort lo = bf16_rn(h - bf16_f(hi));
                const int sw = (e << 6) | (j ^ ((e & 7) << 3));
                Hh[sw] = hi; Hl[sw] = lo;
            }
        }
        __syncthreads();

        // MFMA: wave wv owns edges [eb, eb+16)
        const int eb = wv * 16;
        bf16x8 ah[2], al[2];
        #pragma unroll
        for (int ks = 0; ks < 2; ++ks) {
            const int row = eb + c;
            const int kb  = ks*32 + g*8;
            const int ad  = (row << 6) | (kb ^ ((row & 7) << 3));
            ah[ks] = *(const bf16x8*)&Hh[ad];
            al[ks] = *(const bf16x8*)&Hl[ad];
        }
        f32x4 accf[8];
        #pragma unroll
        for (int nt = 0; nt < 8; ++nt) accf[nt] = (f32x4){0.f, 0.f, 0.f, 0.f};
        #pragma unroll
        for (int nt = 0; nt < 8; ++nt) {
            const int n = nt*16 + c;
            #pragma unroll
            for (int ks = 0; ks < 2; ++ks) {
                const int kb = ks*32 + g*8;
                const int bd = (n << 6) | (kb ^ ((n & 7) << 3));
                const bf16x8 bh = *(const bf16x8*)&W2hl[bd];
                const bf16x8 bl = *(const bf16x8*)&W2hl[8192 + bd];
                accf[nt] = __builtin_amdgcn_mfma_f32_16x16x32_bf16(ah[ks], bh, accf[nt], 0, 0, 0);
                accf[nt] = __builtin_amdgcn_mfma_f32_16x16x32_bf16(al[ks], bh, accf[nt], 0, 0, 0);
                accf[nt] = __builtin_amdgcn_mfma_f32_16x16x32_bf16(ah[ks], bl, accf[nt], 0, 0, 0);
            }
        }

        if (ph == 0) {
            // fused logit: logit = (P_e . t[dst]) * 0.125/64
            float contrib[4] = {0.f, 0.f, 0.f, 0.f};
            #pragma unroll
            for (int r = 0; r < 4; ++r) {
                const int el  = eb + g*4 + r;
                const int dst = sdst[el], src = ssrc[el];
                const float a0  = seat[el][0], a1x = seat[el][1];
                const float a1y = seat[el][2], a1z = seat[el][3];
                const float* tp = t + (size_t)dst * 256;
                const float* np = node_f + (size_t)src * 128;
                #pragma unroll
                for (int hf = 0; hf < 2; ++hf) {
                    const int v = c + 16*hf;
                    const float A0 = accf[0+hf][r], A1 = accf[2+hf][r];
                    const float A2 = accf[4+hf][r], A3 = accf[6+hf][r];
                    const float4 t4a = *(const float4*)(tp + v*8);
                    const float4 t4b = *(const float4*)(tp + v*8 + 4);
                    const float s_v = np[v];
                    const float vx = np[32+3*v], vy = np[33+3*v], vz = np[34+3*v];
                    const float svd = vx*a1x + vy*a1y + vz*a1z;
                    contrib[r] += t4a.x * (A0 * s_v * a0)
                                + t4a.y * (A3 * svd * INV3)
                                + (A1 * s_v) * (t4a.z*a1x + t4a.w*a1y + t4b.x*a1z)
                                + (A2 * a0)  * (t4b.y*vx + t4b.z*vy + t4b.w*vz);
                }
            }
            #pragma unroll
            for (int r = 0; r < 4; ++r) {
                #pragma unroll
                for (int m = 1; m < 16; m <<= 1)
                    contrib[r] += __shfl_xor(contrib[r], m, 64);
            }
            if (c == 0) {
                #pragma unroll
                for (int r = 0; r < 4; ++r) {
                    const int el = eb + g*4 + r;
                    const float logit = contrib[r] * (0.125f / 64.0f);
                    const float ex = cut[el] * expf(logit);
                    sexp[el] = ex;
                    unsafeAtomicAdd(&z[sdst[el]], ex);
                }
            }
        } else {
            // ---- fused value accumulation ----
            __syncthreads();                     // all W2hl frag reads done
            float* U = (float*)W2hl;             // 32 slots x 256 comps
            for (int i = tid; i < 8192; i += 256) U[i] = 0.f;
            __syncthreads();

            const int elb = eb + g*4;
            const int sl0 = slot[elb], sl3 = slot[elb + 3];
            if (sl0 == sl3 && sl0 < 32) {
                // fast path: lane's 4 edges share dst -> pre-reduce in regs
                float vs[16];
                #pragma unroll
                for (int i = 0; i < 16; ++i) vs[i] = 0.f;
                #pragma unroll
                for (int r = 0; r < 4; ++r) {
                    const int el = elb + r;
                    const float cf = sqrtf(sexp[el]) * 0.125f;
                    const float a0 = seat[el][0], a1x = seat[el][1];
                    const float a1y = seat[el][2], a1z = seat[el][3];
                    const float* np = node_f + (size_t)ssrc[el] * 128;
                    #pragma unroll
                    for (int hf = 0; hf < 2; ++hf) {
                        const int v = c + 16*hf;
                        const float A0 = accf[0+hf][r], A1 = accf[2+hf][r];
                        const float A2 = accf[4+hf][r], A3 = accf[6+hf][r];
                        const float s_v = np[v];
                        const float vx = np[32+3*v], vy = np[33+3*v], vz = np[34+3*v];
                        const float svd = vx*a1x + vy*a1y + vz*a1z;
                        const float t1 = cf * A1 * s_v;
                        const float t2 = cf * A2 * a0;
                        vs[hf*8+0] += cf * A0 * s_v * a0;
                        vs[hf*8+1] += cf * A3 * svd * INV3;
                        vs[hf*8+2] += t1 * a1x; vs[hf*8+3] += t1 * a1y; vs[hf*8+4] += t1 * a1z;
                        vs[hf*8+5] += t2 * vx;  vs[hf*8+6] += t2 * vy;  vs[hf*8+7] += t2 * vz;
                    }
                }
                #pragma unroll
                for (int hf = 0; hf < 2; ++hf) {
                    float* u = U + sl0*256 + (c + 16*hf)*8;
                    #pragma unroll
                    for (int jj = 0; jj < 8; ++jj) atomicAdd(&u[jj], vs[hf*8+jj]);
                }
            } else {
                #pragma unroll
                for (int r = 0; r < 4; ++r) {
                    const int el = elb + r;
                    const int sl = slot[el];
                    const float cf = sqrtf(sexp[el]) * 0.125f;
                    const float a0 = seat[el][0], a1x = seat[el][1];
                    const float a1y = seat[el][2], a1z = seat[el][3];
                    const float* np = node_f + (size_t)ssrc[el] * 128;
                    #pragma unroll
                    for (int hf = 0; hf < 2; ++hf) {
                        const int v = c + 16*hf;
                        const float A0 = accf[0+hf][r], A1 = accf[2+hf][r];
                        const float A2 = accf[4+hf][r], A3 = accf[6+hf][r];
                        const float s_v = np[v];
                        const float vx = np[32+3*v], vy = np[33+3*v], vz = np[34+3*v];
                        const float svd = vx*a1x + vy*a1y + vz*a1z;
                        const float t1 = cf * A1 * s_v;
                        const float t2 = cf * A2 * a0;
                        float val[8];
                        val[0] = cf * A0 * s_v * a0;
                        val[1] = cf * A3 * svd * INV3;
                        val[2] = t1 * a1x; val[3] = t1 * a1y; val[4] = t1 * a1z;
                        val[5] = t2 * vx;  val[6] = t2 * vy;  val[7] = t2 * vz;
                        if (sl < 32) {
                            float* u = U + sl*256 + v*8;
                            #pragma unroll
                            for (int jj = 0; jj < 8; ++jj) atomicAdd(&u[jj], val[jj]);
                        } else {
                            float* gp = accg + (size_t)sdst[el]*256 + v*8;
                            #pragma unroll
                            for (int jj = 0; jj < 8; ++jj) unsafeAtomicAdd(&gp[jj], val[jj]);
                        }
                    }
                }
            }
            __syncthreads();
            // flush: store if dst fully inside this block, atomic otherwise
            const int nsl = min(nslots_s, 32);
            for (int s = 0; s < nsl; ++s) {
                const int d = sdstu[s];
                const float uv = U[s*256 + tid];
                float* gp = accg + (size_t)d*256 + tid;
                if (rowptr[d] >= e0 && rowptr[d+1] <= e0 + 64) *gp = uv;
                else unsafeAtomicAdd(gp, uv);
            }
        }
    }
}

// ---------------- K3: final node linears (acc in [v][8] layout, /sqrt(z)) ----
__global__ __launch_bounds__(256) void node_out_kernel(
    const float* __restrict__ accg,    // (NN,256) [v][8]
    const float* __restrict__ z,
    const float* __restrict__ lin_ws,  // (64,32)
    const float* __restrict__ lin_wv,  // (64,32)
    float* __restrict__ out)           // (NN,128)
{
    __shared__ float sa[8][256];
    const int tid = threadIdx.x;
    const int nb = blockIdx.x * 8;
    for (int i = tid; i < 8*256; i += 256) sa[i >> 8][i & 255] = accg[(size_t)nb*256 + i];
    __syncthreads();

    const int nl = tid >> 5, o = tid & 31;
    const int n = nb + nl;
    const float* a8 = sa[nl];

    float zv = z[n];
    if (zv == 0.f) zv = 1.f;
    const float rsq = rsqrtf(zv) * 0.125f;

    float os = 0.f, ov0 = 0.f, ov1 = 0.f, ov2 = 0.f;
    #pragma unroll
    for (int u = 0; u < 32; ++u) {
        const float* r8 = a8 + u*8;
        os = fmaf(r8[0], lin_ws[u*32 + o], os);
        os = fmaf(r8[1], lin_ws[(32+u)*32 + o], os);
        const float w0 = lin_wv[u*32 + o];
        ov0 = fmaf(r8[2], w0, ov0); ov1 = fmaf(r8[3], w0, ov1); ov2 = fmaf(r8[4], w0, ov2);
        const float w1 = lin_wv[(32+u)*32 + o];
        ov0 = fmaf(r8[5], w1, ov0); ov1 = fmaf(r8[6], w1, ov1); ov2 = fmaf(r8[7], w1, ov2);
    }
    float* on = out + (size_t)n * 128;
    on[o]            = os  * rsq;
    on[32 + 3*o + 0] = ov0 * rsq;
    on[32 + 3*o + 1] = ov1 * rsq;
    on[32 + 3*o + 2] = ov2 * rsq;
}

extern "C" void kernel_launch(void* const* d_in, const int* in_sizes, int n_in,
                              void* d_out, int out_size, void* d_ws, size_t ws_size,
                              hipStream_t stream) {
    const int*   esrc    = (const int*)  d_in[0];
    const int*   edst    = (const int*)  d_in[1];
    const float* xattr   = (const float*)d_in[2];
    const float* eattr   = (const float*)d_in[3];
    const float* cutoff  = (const float*)d_in[4];
    const float* node_f  = (const float*)d_in[5];
    const float* k_w1    = (const float*)d_in[6];
    const float* k_w2    = (const float*)d_in[7];
    const float* v_w1    = (const float*)d_in[8];
    const float* v_w2    = (const float*)d_in[9];
    const float* w_ss    = (const float*)d_in[10];
    const float* w_vv    = (const float*)d_in[11];
    const float* lin_ws  = (const float*)d_in[12];
    const float* lin_wv  = (const float*)d_in[13];
    float* out = (float*)d_out;

    // ws (~43 MB): floats [t NN*256 | acc NN*256 | z NN] | ushort w2img 32768 |
    //              ints [cnt NN | rowptr NN+1 | woff NN | perm NE | bsum | boff]
    float*  t     = (float*)d_ws;
    float*  accg  = t + (size_t)NN * 256;
    float*  z     = accg + (size_t)NN * 256;
    ushort* w2img = (ushort*)(z + NN);
    int*    cnt    = (int*)(w2img + 32768);
    int*    rowptr = cnt + NN;
    int*    woff   = rowptr + NN + 1;
    int*    perm   = woff + NN;
    int*    bsum   = perm + NE;
    int*    boff   = bsum + 128;

    hipMemsetAsync(accg, 0, ((size_t)NN * 256 + NN) * sizeof(float), stream); // acc+z
    hipMemsetAsync(cnt, 0, NN * sizeof(int), stream);

    node_transform_kernel<<<(NN*32 + 255)/256, 256, 0, stream>>>(node_f, w_ss, w_vv, t);
    w2img_kernel<<<64, 256, 0, stream>>>(k_w2, v_w2, w2img);

    hist_kernel<<<(NE + 255)/256, 256, 0, stream>>>(edst, cnt);
    scanA_kernel<<<(NN + 255)/256, 256, 0, stream>>>(cnt, rowptr, bsum);
    scanB_kernel<<<1, 128, 0, stream>>>(bsum, boff, rowptr);
    scanC_kernel<<<(NN + 255)/256, 256, 0, stream>>>(rowptr, boff, woff);
    scatter_kernel<<<(NE + 255)/256, 256, 0, stream>>>(edst, woff, perm);

    edge_gemm_kernel<<<NE/64, 256, 0, stream>>>(
        perm, esrc, edst, xattr, eattr, cutoff, node_f,
        k_w1, v_w1, w2img, t, rowptr, z, accg);

    node_out_kernel<<<NN/8, 256, 0, stream>>>(accg, z, lin_ws, lin_wv, out);
}